// Round 2
// baseline (120.058 us; speedup 1.0000x reference)
//
#include <hip/hip_runtime.h>

// SobelLoss: mean over 3 dirs of mean |sobel(moved) - sobel(label)|.
// conv(m)-conv(l) = conv(m-l); separable: s=[1,2,1], d=[-1,0,1]:
//   gx = sH(dW) rolled sD;  gy = dH(sW) rolled sD;  gz = sH(sW) rolled -dD.
//
// R12: LDS row-sharing to kill H-overfetch. R10/R11 decomposition:
// timed 112.8us = 2x42.5 harness poison fills (untouchable) + ~3 reduce
// + ~25us sobel. Unique bytes = 78.6MB = 12.5us @6.3TB/s; old per-wave
// register buffers re-fetched rows (H x1.5, D x1.25, W x1.2 = x2.25 =
// 177MB ~ 28us => fetch-bound on redundant traffic). Now: block stages
// 18 rows x 64 cols x 2 inputs per plane into LDS via global_load_lds
// (wave-uniform LDS dest + per-lane clamped global src), 4 waves share
// => fetch 132.7MB (-25%).
// Pipeline: 4 rotating plane slots, 2-ahead prefetch; per plane each wave
// issues 9 loads, then asm s_waitcnt vmcnt(18) (drain ONLY the plane
// being computed; 18 stay in flight) + raw s_barrier. NEVER __syncthreads
// in-loop (implicit vmcnt(0) would drain the pipeline). Stage-before-
// barrier + 4 slots => overwritten slot was last read 2 barriers ago =>
// race-free with ONE barrier per plane.
// HARD-WON RULES: no min-waves __launch_bounds__ clamp (R2/R4 spill);
// "memory" clobber on the waitcnt asm pins both the STAGE intrinsics
// above it and the ds_reads below it.

#define BB 2
#define DD 160
#define HH 192
#define WW 160
#define HW (HH * WW)

#define TH 4                    // output H rows per thread (per wave)
#define DC 8                    // output D planes per block
#define NIT (DC + 2)            // 10
#define NR (TH + 2)             // 6 rows read per wave per plane
#define BH 16                   // block output rows = 4 waves * TH
#define BIN 18                  // staged input rows = BH + 2
#define NSLOT 4                 // rotating plane slots in LDS
#define NTHREADS 256            // 4 waves/block

#define NBLK (36 * (DD / DC) * BB)   // 1440 partials

__global__ __launch_bounds__(NTHREADS)
void sobel_loss_kernel(const float* __restrict__ moved,
                       const float* __restrict__ label,
                       float* __restrict__ out,
                       float* __restrict__ part)   // nullptr => atomic path
{
    __shared__ float lds[NSLOT][2][BIN][64];   // 36,864 B
    __shared__ float red[4];

    const int tid   = threadIdx.x;
    const int lane  = tid & 63;
    const int wavei = tid >> 6;                 // 0..3
    const int wch   = blockIdx.x % 3;           // W chunk: 62 outputs each
    const int hgrp  = blockIdx.x / 3;           // 0..11
    const int hbase0 = hgrp * BH;               // block's first output row
    const int d0    = blockIdx.y * DC;          // 20 chunks
    const int base_b = blockIdx.z * (DD * HW);

    // lane l holds column w = w0 + l - 1; outputs live on lanes 1..62
    const int  w0 = wch * 62;                   // 0, 62, 124
    const int  w  = w0 + lane - 1;              // -1 .. 186
    const bool wv = (unsigned)w < (unsigned)WW;
    const int  gw = min(max(w, 0), WW - 1);
    const bool outv = (lane >= 1) && (lane <= 62) && (w < WW);

    // ---- staging role: wave loads input (wavei>>1), rows rbase..rbase+8 ----
    const float* __restrict__ sbase = (wavei & 2) ? label : moved;
    const int sinp  = wavei >> 1;               // 0=moved, 1=label
    const int rbase = (wavei & 1) * 9;          // rows 0..8 or 9..17

    // per-load element offsets (row clamped to [0,HH-1]); plane-independent.
    // jj is compile-time in all uses -> stays in registers.
    int roff[9];
#pragma unroll
    for (int jj = 0; jj < 9; ++jj) {
        const int gh = min(max(hbase0 - 1 + rbase + jj, 0), HH - 1);
        roff[jj] = gh * WW + gw;
    }

    // ---- compute-side row validity for this wave ----
    const int r0 = wavei * TH;                  // local row base in tile
    bool rv[NR];
#pragma unroll
    for (int rr = 0; rr < NR; ++rr) {
        const int gh = hbase0 - 1 + r0 + rr;
        rv[rr] = (unsigned)gh < (unsigned)HH;
    }

    // STAGE: 9 global->LDS dword DMAs for this wave (one plane's share).
    // LDS dest is wave-uniform; HW scatters lane*4. Global src per-lane.
#define STAGE(slot, p) do {                                                  \
        const int pp_ = min(max((p), 0), DD - 1);                            \
        const float* pb_ = sbase + base_b + pp_ * HW;                        \
        _Pragma("unroll")                                                    \
        for (int jj = 0; jj < 9; ++jj) {                                     \
            __builtin_amdgcn_global_load_lds(                                \
                (const __attribute__((address_space(1))) void*)(pb_ + roff[jj]), \
                (__attribute__((address_space(3))) void*)                    \
                    (&lds[slot][sinp][rbase + jj][0]),                       \
                4, 0, 0);                                                    \
        }                                                                    \
    } while (0)

    STAGE(0, d0 - 1);
    STAGE(1, d0);
    // outstanding vmem: 18 per wave

    float px1[TH], px2[TH], py1[TH], py2[TH], pz1[TH], pz2[TH];
#pragma unroll
    for (int i = 0; i < TH; ++i) {
        px1[i] = px2[i] = 0.f;
        py1[i] = py2[i] = 0.f;
        pz1[i] = pz2[i] = 0.f;
    }
    float acc = 0.f;

#pragma unroll
    for (int it = 0; it < NIT; ++it) {
        const int s  = it & 3;          // slot to compute (plane d0-1+it)
        const int s2 = (it + 2) & 3;    // slot to stage   (plane d0+1+it)

        STAGE(s2, d0 + 1 + it);         // outstanding: 27

        // drain ONLY this plane's 18->9-per-wave oldest loads; keep 18 in
        // flight. "memory" clobber pins STAGE above, ds_reads below.
        asm volatile("s_waitcnt vmcnt(18)" ::: "memory");
        __builtin_amdgcn_s_barrier();

        // ---- compute plane p = d0-1+it from LDS slot s ----
        const bool pv = (unsigned)(d0 - 1 + it) < (unsigned)DD;
        float sW[NR], dW[NR];
#pragma unroll
        for (int rr = 0; rr < NR; ++rr) {
            const float m = lds[s][0][r0 + rr][lane];
            const float l = lds[s][1][r0 + rr][lane];
            const float d = (pv && rv[rr] && wv) ? (m - l) : 0.f;
            const float dl = __shfl_up(d, 1, 64);    // w-1 (lane 0 junk)
            const float dr = __shfl_down(d, 1, 64);  // w+1 (lane 63 junk)
            sW[rr] = (dl + dr) + 2.f * d;   // W-smooth
            dW[rr] = dr - dl;               // W-deriv
        }
#pragma unroll
        for (int i = 0; i < TH; ++i) {
            const float px = (dW[i] + dW[i + 2]) + 2.f * dW[i + 1];  // sH(dW)
            const float pz = (sW[i] + sW[i + 2]) + 2.f * sW[i + 1];  // sH(sW)
            const float py = sW[i + 2] - sW[i];                      // dH(sW)
            if (it >= 2 && outv) {
                const float gx = px2[i] + 2.f * px1[i] + px;   // sD
                const float gy = py2[i] + 2.f * py1[i] + py;   // sD
                const float gz = pz2[i] - pz;                  // dD
                acc += fabsf(gx) + fabsf(gy) + fabsf(gz);
            }
            px2[i] = px1[i]; px1[i] = px;
            py2[i] = py1[i]; py1[i] = py;
            pz2[i] = pz1[i]; pz1[i] = pz;
        }
    }

    // drain the 18 tail loads before the final barrier / reduction
    asm volatile("s_waitcnt vmcnt(0)" ::: "memory");

    // ---- reduce: wave shuffle -> tiny LDS -> one store per block ----
#pragma unroll
    for (int off = 32; off > 0; off >>= 1)
        acc += __shfl_down(acc, off, 64);
    if (lane == 0) red[wavei] = acc;
    __syncthreads();
    if (tid == 0) {
        const float s = red[0] + red[1] + red[2] + red[3];
        if (part) {
            part[blockIdx.x + gridDim.x * (blockIdx.y +
                 (size_t)gridDim.y * blockIdx.z)] = s;
        } else {
            atomicAdd(out, s * (1.0f / (3.0f * BB * DD * HH * WW)));
        }
    }
#undef STAGE
}

// Single-block final reduce: sum NBLK partials, scale, write out directly.
__global__ __launch_bounds__(256)
void sobel_reduce_kernel(const float* __restrict__ part,
                         float* __restrict__ out)
{
    __shared__ float red[4];
    float a = 0.f;
    for (int i = threadIdx.x; i < NBLK; i += 256)
        a += part[i];
#pragma unroll
    for (int off = 32; off > 0; off >>= 1)
        a += __shfl_down(a, off, 64);
    const int lane = threadIdx.x & 63;
    if (lane == 0) red[threadIdx.x >> 6] = a;
    __syncthreads();
    if (threadIdx.x == 0)
        out[0] = (red[0] + red[1] + red[2] + red[3])
                 * (1.0f / (3.0f * BB * DD * HH * WW));
}

extern "C" void kernel_launch(void* const* d_in, const int* in_sizes, int n_in,
                              void* d_out, int out_size, void* d_ws, size_t ws_size,
                              hipStream_t stream) {
    const float* moved = (const float*)d_in[0];
    const float* label = (const float*)d_in[1];
    float* out = (float*)d_out;
    (void)in_sizes; (void)n_in; (void)out_size;

    // x: 3 W-chunks * 12 H-groups; y: 20 D-chunks; z: batch
    dim3 grid(36, DD / DC, BB);     // 1440 four-wave blocks

    if (d_ws != nullptr && ws_size >= NBLK * sizeof(float)) {
        float* part = (float*)d_ws;
        sobel_loss_kernel<<<grid, NTHREADS, 0, stream>>>(moved, label, out, part);
        sobel_reduce_kernel<<<1, 256, 0, stream>>>(part, out);
    } else {
        hipMemsetAsync(out, 0, sizeof(float), stream);
        sobel_loss_kernel<<<grid, NTHREADS, 0, stream>>>(moved, label, out, nullptr);
    }
}

// Round 3
// 112.009 us; speedup vs baseline: 1.0719x; 1.0719x over previous
//
#include <hip/hip_runtime.h>

// SobelLoss: mean over 3 dirs of mean |sobel(moved) - sobel(label)|.
// conv(m)-conv(l) = conv(m-l); separable: s=[1,2,1], d=[-1,0,1]:
//   gx = sH(dW) rolled sD;  gy = dH(sW) rolled sD;  gz = sH(sW) rolled -dD.
//
// R13: REVERT to R10/R11 register pipeline (proven ~23us sobel) + XCD-
// contiguous block swizzle. R12 post-mortem: LDS row-sharing cut addressed
// bytes 177->133MB yet REGRESSED (+11us) => kernel is NOT fetch-volume
// bound; per-plane s_barrier coupled waves + LDS round-trip added latency.
// Remaining gap (23us vs 12.5us unique-byte floor) blamed on CROSS-XCD
// halo refetch: neighbor tiles land on different (non-coherent) XCD L2s
// under round-robin dispatch, so halo lines re-fetch from HBM.
// Fix: flat 1440-block grid; swz=(b&7)*180+(b>>3) gives each XCD 180
// consecutive work-ids = 5 full (z,d-chunk) slabs of 36 tiles; slab
// working set ~2.5MB < 4MB per-XCD L2 => H/W (and most D) halos L2-hit.
//
// Pipeline (R10, unchanged): asm global_load_dword pins issue order;
// s_waitcnt vmcnt(24) drains only the oldest plane (12 loads), keeping 24
// loads (6KB/wave) permanently in flight; "+v" ties stop compute hoisting.
// HARD-WON RULES: no min-waves __launch_bounds__ clamp (R2/R4 spill);
// NEVER __syncthreads in-loop; no in-graph memset (R11: partials->ws).

#define BB 2
#define DD 160
#define HH 192
#define WW 160
#define HW (HH * WW)

#define TH 4                    // output H rows per thread
#define DC 8                    // output D planes per wave
#define NIT (DC + 2)            // 10
#define NR (TH + 2)             // 6 rows live per plane
#define NTHREADS 256            // 4 waves/block (R7's best packing)

#define NBLK (36 * (DD / DC) * BB)   // 1440 partials
#define PER_XCD (NBLK / 8)           // 180 consecutive work-ids per XCD

#define GLOAD(dst, vo, sb) \
    asm volatile("global_load_dword %0, %1, %2" \
                 : "=v"(dst) : "v"(vo), "s"(sb) : "memory")

__global__ __launch_bounds__(NTHREADS)
__attribute__((amdgpu_waves_per_eu(1, 4)))
void sobel_loss_kernel(const float* __restrict__ moved,
                       const float* __restrict__ label,
                       float* __restrict__ out,
                       float* __restrict__ part)   // nullptr => atomic path
{
    __shared__ float red[4];

    // ---- XCD-contiguous work-id swizzle (bijective: 1440 % 8 == 0) ----
    // HW round-robins blockIdx across 8 XCDs; block b -> work id
    // (b&7)*180 + (b>>3), so XCD k processes ids [k*180, k*180+180) in
    // order: x-fastest => W-chunk then H-group then D-slab locality.
    const int flat = blockIdx.x;
    const int swz  = (flat & 7) * PER_XCD + (flat >> 3);
    const int bx   = swz % 36;           // tile: wch + 3*hgrp
    const int by   = (swz / 36) % (DD / DC);
    const int bz   = swz / (36 * (DD / DC));

    const int tid   = threadIdx.x;
    const int lane  = tid & 63;
    const int wavei = tid >> 6;                 // 0..3
    const int wch   = bx % 3;                   // W chunk: 62 outputs each
    const int hgrp  = bx / 3;                   // 0..11
    const int hbase = (hgrp * 4 + wavei) * TH;  // 0..188
    const int d0    = by * DC;                  // 20 chunks
    const int base_b = bz * (DD * HW);

    // lane l holds column w = w0 + l - 1; outputs live on lanes 1..62
    const int  w0 = wch * 62;                   // 0, 62, 124
    const int  w  = w0 + lane - 1;              // -1 .. 186
    const bool wv = (unsigned)w < (unsigned)WW;
    const int  gw = min(max(w, 0), WW - 1);
    const bool outv = (lane >= 1) && (lane <= 62) && (w < WW);

    // per-row byte voffsets (fixed across D); OOB rows clamped, masked later
    int  voff[NR];
    bool rv[NR];
#pragma unroll
    for (int r = 0; r < NR; ++r) {
        const int gh = hbase - 1 + r;
        rv[r] = (unsigned)gh < (unsigned)HH;
        voff[r] = (min(max(gh, 0), HH - 1) * WW + gw) * 4;
    }

    // 3 rotating plane buffers; slot s computed at iters with it%3==s
    float bm[3][NR], bl[3][NR];

    {   // preload slot0 = plane d0-1 (clamped), slot1 = plane d0
        const float* pm = moved + base_b + max(d0 - 1, 0) * HW;
        const float* pl = label + base_b + max(d0 - 1, 0) * HW;
#pragma unroll
        for (int r = 0; r < NR; ++r) {
            GLOAD(bm[0][r], voff[r], pm);
            GLOAD(bl[0][r], voff[r], pl);
        }
        const float* qm = moved + base_b + d0 * HW;
        const float* ql = label + base_b + d0 * HW;
#pragma unroll
        for (int r = 0; r < NR; ++r) {
            GLOAD(bm[1][r], voff[r], qm);
            GLOAD(bl[1][r], voff[r], ql);
        }
    }   // outstanding: 24

    float px1[TH], px2[TH], py1[TH], py2[TH], pz1[TH], pz2[TH];
#pragma unroll
    for (int i = 0; i < TH; ++i) {
        px1[i] = px2[i] = 0.f;
        py1[i] = py2[i] = 0.f;
        pz1[i] = pz2[i] = 0.f;
    }
    float acc = 0.f;

#pragma unroll
    for (int it = 0; it < NIT; ++it) {
        const int s  = it % 3;          // slot to compute (plane d0-1+it)
        const int s2 = (it + 2) % 3;    // slot to issue (plane d0+1+it)

        // ---- issue next-next plane (clamped addr; uniform 12 loads) ----
        {
            const int p = min(d0 + it + 1, DD - 1);
            const float* pm = moved + base_b + p * HW;
            const float* pl = label + base_b + p * HW;
#pragma unroll
            for (int r = 0; r < NR; ++r) {
                GLOAD(bm[s2][r], voff[r], pm);
                GLOAD(bl[s2][r], voff[r], pl);
            }
        }   // outstanding: 36

        // ---- wait ONLY the oldest 12 (slot s); keep 24 in flight.
        //      "+v" ties force compute below to stay below this wait. ----
        asm volatile("s_waitcnt vmcnt(24)"
            : "+v"(bm[s][0]), "+v"(bm[s][1]), "+v"(bm[s][2]),
              "+v"(bm[s][3]), "+v"(bm[s][4]), "+v"(bm[s][5]),
              "+v"(bl[s][0]), "+v"(bl[s][1]), "+v"(bl[s][2]),
              "+v"(bl[s][3]), "+v"(bl[s][4]), "+v"(bl[s][5]));

        // ---- compute plane p = d0-1+it ----
        const bool pv = (unsigned)(d0 - 1 + it) < (unsigned)DD;
        float sW[NR], dW[NR];
#pragma unroll
        for (int r = 0; r < NR; ++r) {
            const float d  = (pv && rv[r] && wv) ? (bm[s][r] - bl[s][r]) : 0.f;
            const float dl = __shfl_up(d, 1, 64);    // w-1 (lane 0 junk, masked)
            const float dr = __shfl_down(d, 1, 64);  // w+1 (lane 63 junk, masked)
            sW[r] = (dl + dr) + 2.f * d;   // W-smooth
            dW[r] = dr - dl;               // W-deriv
        }
#pragma unroll
        for (int i = 0; i < TH; ++i) {
            const float px = (dW[i] + dW[i + 2]) + 2.f * dW[i + 1];  // sH(dW)
            const float pz = (sW[i] + sW[i + 2]) + 2.f * sW[i + 1];  // sH(sW)
            const float py = sW[i + 2] - sW[i];                      // dH(sW)
            if (it >= 2 && outv) {
                const float gx = px2[i] + 2.f * px1[i] + px;   // sD
                const float gy = py2[i] + 2.f * py1[i] + py;   // sD
                const float gz = pz2[i] - pz;                  // dD: (q-1)-(q+1)
                acc += fabsf(gx) + fabsf(gy) + fabsf(gz);
            }
            px2[i] = px1[i]; px1[i] = px;
            py2[i] = py1[i]; py1[i] = py;
            pz2[i] = pz1[i]; pz1[i] = pz;
        }
    }

    // drain the 24 tail loads before reusing the memory pipe / ending
    asm volatile("s_waitcnt vmcnt(0)" ::: "memory");

    // ---- reduce: wave shuffle -> tiny LDS -> one store per block ----
#pragma unroll
    for (int off = 32; off > 0; off >>= 1)
        acc += __shfl_down(acc, off, 64);
    if (lane == 0) red[wavei] = acc;
    __syncthreads();
    if (tid == 0) {
        const float s = red[0] + red[1] + red[2] + red[3];
        if (part) {
            part[swz] = s;   // swz is a bijection of [0,NBLK)
        } else {
            atomicAdd(out, s * (1.0f / (3.0f * BB * DD * HH * WW)));
        }
    }
}

// Single-block final reduce: sum NBLK partials, scale, write out directly.
__global__ __launch_bounds__(256)
void sobel_reduce_kernel(const float* __restrict__ part,
                         float* __restrict__ out)
{
    __shared__ float red[4];
    float a = 0.f;
    for (int i = threadIdx.x; i < NBLK; i += 256)
        a += part[i];
#pragma unroll
    for (int off = 32; off > 0; off >>= 1)
        a += __shfl_down(a, off, 64);
    const int lane = threadIdx.x & 63;
    if (lane == 0) red[threadIdx.x >> 6] = a;
    __syncthreads();
    if (threadIdx.x == 0)
        out[0] = (red[0] + red[1] + red[2] + red[3])
                 * (1.0f / (3.0f * BB * DD * HH * WW));
}

extern "C" void kernel_launch(void* const* d_in, const int* in_sizes, int n_in,
                              void* d_out, int out_size, void* d_ws, size_t ws_size,
                              hipStream_t stream) {
    const float* moved = (const float*)d_in[0];
    const float* label = (const float*)d_in[1];
    float* out = (float*)d_out;
    (void)in_sizes; (void)n_in; (void)out_size;

    // flat 1D grid so the in-kernel XCD swizzle controls work placement
    dim3 grid(NBLK, 1, 1);          // 1440 four-wave blocks = 5760 waves

    if (d_ws != nullptr && ws_size >= NBLK * sizeof(float)) {
        float* part = (float*)d_ws;
        sobel_loss_kernel<<<grid, NTHREADS, 0, stream>>>(moved, label, out, part);
        sobel_reduce_kernel<<<1, 256, 0, stream>>>(part, out);
    } else {
        hipMemsetAsync(out, 0, sizeof(float), stream);
        sobel_loss_kernel<<<grid, NTHREADS, 0, stream>>>(moved, label, out, nullptr);
    }
}

// Round 4
// 108.089 us; speedup vs baseline: 1.1107x; 1.0363x over previous
//
#include <hip/hip_runtime.h>

// SobelLoss: mean over 3 dirs of mean |sobel(moved) - sobel(label)|.
// conv(m)-conv(l) = conv(m-l); separable: s=[1,2,1], d=[-1,0,1]:
//   gx = sH(dW) rolled sD;  gy = dH(sW) rolled sD;  gz = sH(sW) rolled -dD.
//
// R14: shrink HBM-LEVEL redundancy. History: R12 (LDS sharing, -25%
// addressed) REGRESSED; R13 (XCD swizzle) NULL => locality theories dead;
// caches already absorb intra-block halos. Effective HBM traffic model:
// unique 78.6MB x H(block halo 18/16=1.125) x D(10/8=1.25) x W(1.02)
// ~= 113MB -> 17.9us floor; measured ~23us => ~78% eff. Levers that reach
// HBM: D halo and block-level H halo. So: DC 8->16 (D x1.125), TH 4->6
// (block 24 rows, fetch 26 => H x1.083) => ~98MB, 15.5us floor.
// 480 blocks (24 tiles x 10 dchunks x 2 batch) all-resident one-shot.
//
// Pipeline (R10, unchanged): asm global_load_dword pins issue order;
// 3 rotating plane slots, 2-ahead prefetch; s_waitcnt vmcnt(32) drains
// only the oldest plane (16 loads), keeping 32 loads in flight; "+v"
// ties stop compute hoisting above the wait.
// HARD-WON RULES: no min-waves __launch_bounds__ clamp (R2/R4 spill);
// NEVER __syncthreads in-loop; no in-graph memset (R11: partials->ws);
// keep it-loop fully unrolled (runtime slot index => scratch, rule #20).

#define BB 2
#define DD 160
#define HH 192
#define WW 160
#define HW (HH * WW)

#define TH 6                    // output H rows per thread
#define DC 16                   // output D planes per block
#define NIT (DC + 2)            // 18
#define NR (TH + 2)             // 8 rows live per plane per wave
#define BH (4 * TH)             // 24 block output rows
#define HGRPS (HH / BH)         // 8
#define TILES (3 * HGRPS)       // 24 (wch + 3*hgrp)
#define DCH (DD / DC)           // 10
#define NTHREADS 256            // 4 waves/block

#define NBLK (TILES * DCH * BB)      // 480 partials
#define PER_XCD (NBLK / 8)           // 60 consecutive work-ids per XCD

#define GLOAD(dst, vo, sb) \
    asm volatile("global_load_dword %0, %1, %2" \
                 : "=v"(dst) : "v"(vo), "s"(sb) : "memory")

__global__ __launch_bounds__(NTHREADS)
__attribute__((amdgpu_waves_per_eu(1, 4)))
void sobel_loss_kernel(const float* __restrict__ moved,
                       const float* __restrict__ label,
                       float* __restrict__ out,
                       float* __restrict__ part)   // nullptr => atomic path
{
    __shared__ float red[4];

    // ---- XCD-contiguous work-id swizzle (bijective: 480 % 8 == 0) ----
    const int flat = blockIdx.x;
    const int swz  = (flat & 7) * PER_XCD + (flat >> 3);
    const int bx   = swz % TILES;        // tile: wch + 3*hgrp
    const int by   = (swz / TILES) % DCH;
    const int bz   = swz / (TILES * DCH);

    const int tid   = threadIdx.x;
    const int lane  = tid & 63;
    const int wavei = tid >> 6;                 // 0..3
    const int wch   = bx % 3;                   // W chunk: 62 outputs each
    const int hgrp  = bx / 3;                   // 0..7
    const int hbase = hgrp * BH + wavei * TH;   // 0..186
    const int d0    = by * DC;                  // 10 chunks
    const int base_b = bz * (DD * HW);

    // lane l holds column w = w0 + l - 1; outputs live on lanes 1..62
    const int  w0 = wch * 62;                   // 0, 62, 124
    const int  w  = w0 + lane - 1;              // -1 .. 186
    const bool wv = (unsigned)w < (unsigned)WW;
    const int  gw = min(max(w, 0), WW - 1);
    const bool outv = (lane >= 1) && (lane <= 62) && (w < WW);

    // per-row byte voffsets (fixed across D); OOB rows clamped, masked later
    int  voff[NR];
    bool rv[NR];
#pragma unroll
    for (int r = 0; r < NR; ++r) {
        const int gh = hbase - 1 + r;
        rv[r] = (unsigned)gh < (unsigned)HH;
        voff[r] = (min(max(gh, 0), HH - 1) * WW + gw) * 4;
    }

    // 3 rotating plane buffers; slot s computed at iters with it%3==s
    float bm[3][NR], bl[3][NR];

    {   // preload slot0 = plane d0-1 (clamped), slot1 = plane d0
        const float* pm = moved + base_b + max(d0 - 1, 0) * HW;
        const float* pl = label + base_b + max(d0 - 1, 0) * HW;
#pragma unroll
        for (int r = 0; r < NR; ++r) {
            GLOAD(bm[0][r], voff[r], pm);
            GLOAD(bl[0][r], voff[r], pl);
        }
        const float* qm = moved + base_b + d0 * HW;
        const float* ql = label + base_b + d0 * HW;
#pragma unroll
        for (int r = 0; r < NR; ++r) {
            GLOAD(bm[1][r], voff[r], qm);
            GLOAD(bl[1][r], voff[r], ql);
        }
    }   // outstanding: 32

    float px1[TH], px2[TH], py1[TH], py2[TH], pz1[TH], pz2[TH];
#pragma unroll
    for (int i = 0; i < TH; ++i) {
        px1[i] = px2[i] = 0.f;
        py1[i] = py2[i] = 0.f;
        pz1[i] = pz2[i] = 0.f;
    }
    float acc = 0.f;

#pragma unroll
    for (int it = 0; it < NIT; ++it) {
        const int s  = it % 3;          // slot to compute (plane d0-1+it)
        const int s2 = (it + 2) % 3;    // slot to issue (plane d0+1+it)

        // ---- issue next-next plane (clamped addr; uniform 16 loads) ----
        {
            const int p = min(d0 + it + 1, DD - 1);
            const float* pm = moved + base_b + p * HW;
            const float* pl = label + base_b + p * HW;
#pragma unroll
            for (int r = 0; r < NR; ++r) {
                GLOAD(bm[s2][r], voff[r], pm);
                GLOAD(bl[s2][r], voff[r], pl);
            }
        }   // outstanding: 48

        // ---- wait ONLY the oldest 16 (slot s); keep 32 in flight.
        //      "+v" ties force compute below to stay below this wait. ----
        asm volatile("s_waitcnt vmcnt(32)"
            : "+v"(bm[s][0]), "+v"(bm[s][1]), "+v"(bm[s][2]),
              "+v"(bm[s][3]), "+v"(bm[s][4]), "+v"(bm[s][5]),
              "+v"(bm[s][6]), "+v"(bm[s][7]),
              "+v"(bl[s][0]), "+v"(bl[s][1]), "+v"(bl[s][2]),
              "+v"(bl[s][3]), "+v"(bl[s][4]), "+v"(bl[s][5]),
              "+v"(bl[s][6]), "+v"(bl[s][7]));

        // ---- compute plane p = d0-1+it ----
        const bool pv = (unsigned)(d0 - 1 + it) < (unsigned)DD;
        float sW[NR], dW[NR];
#pragma unroll
        for (int r = 0; r < NR; ++r) {
            const float d  = (pv && rv[r] && wv) ? (bm[s][r] - bl[s][r]) : 0.f;
            const float dl = __shfl_up(d, 1, 64);    // w-1 (lane 0 junk, masked)
            const float dr = __shfl_down(d, 1, 64);  // w+1 (lane 63 junk, masked)
            sW[r] = (dl + dr) + 2.f * d;   // W-smooth
            dW[r] = dr - dl;               // W-deriv
        }
#pragma unroll
        for (int i = 0; i < TH; ++i) {
            const float px = (dW[i] + dW[i + 2]) + 2.f * dW[i + 1];  // sH(dW)
            const float pz = (sW[i] + sW[i + 2]) + 2.f * sW[i + 1];  // sH(sW)
            const float py = sW[i + 2] - sW[i];                      // dH(sW)
            if (it >= 2 && outv) {
                const float gx = px2[i] + 2.f * px1[i] + px;   // sD
                const float gy = py2[i] + 2.f * py1[i] + py;   // sD
                const float gz = pz2[i] - pz;                  // dD: (q-1)-(q+1)
                acc += fabsf(gx) + fabsf(gy) + fabsf(gz);
            }
            px2[i] = px1[i]; px1[i] = px;
            py2[i] = py1[i]; py1[i] = py;
            pz2[i] = pz1[i]; pz1[i] = pz;
        }
    }

    // drain the 32 tail loads before reusing the memory pipe / ending
    asm volatile("s_waitcnt vmcnt(0)" ::: "memory");

    // ---- reduce: wave shuffle -> tiny LDS -> one store per block ----
#pragma unroll
    for (int off = 32; off > 0; off >>= 1)
        acc += __shfl_down(acc, off, 64);
    if (lane == 0) red[wavei] = acc;
    __syncthreads();
    if (tid == 0) {
        const float s = red[0] + red[1] + red[2] + red[3];
        if (part) {
            part[swz] = s;   // swz is a bijection of [0,NBLK)
        } else {
            atomicAdd(out, s * (1.0f / (3.0f * BB * DD * HH * WW)));
        }
    }
}

// Single-block final reduce: sum NBLK partials, scale, write out directly.
__global__ __launch_bounds__(256)
void sobel_reduce_kernel(const float* __restrict__ part,
                         float* __restrict__ out)
{
    __shared__ float red[4];
    float a = 0.f;
    for (int i = threadIdx.x; i < NBLK; i += 256)
        a += part[i];
#pragma unroll
    for (int off = 32; off > 0; off >>= 1)
        a += __shfl_down(a, off, 64);
    const int lane = threadIdx.x & 63;
    if (lane == 0) red[threadIdx.x >> 6] = a;
    __syncthreads();
    if (threadIdx.x == 0)
        out[0] = (red[0] + red[1] + red[2] + red[3])
                 * (1.0f / (3.0f * BB * DD * HH * WW));
}

extern "C" void kernel_launch(void* const* d_in, const int* in_sizes, int n_in,
                              void* d_out, int out_size, void* d_ws, size_t ws_size,
                              hipStream_t stream) {
    const float* moved = (const float*)d_in[0];
    const float* label = (const float*)d_in[1];
    float* out = (float*)d_out;
    (void)in_sizes; (void)n_in; (void)out_size;

    // flat 1D grid so the in-kernel XCD swizzle controls work placement
    dim3 grid(NBLK, 1, 1);          // 480 four-wave blocks, all resident

    if (d_ws != nullptr && ws_size >= NBLK * sizeof(float)) {
        float* part = (float*)d_ws;
        sobel_loss_kernel<<<grid, NTHREADS, 0, stream>>>(moved, label, out, part);
        sobel_reduce_kernel<<<1, 256, 0, stream>>>(part, out);
    } else {
        hipMemsetAsync(out, 0, sizeof(float), stream);
        sobel_loss_kernel<<<grid, NTHREADS, 0, stream>>>(moved, label, out, nullptr);
    }
}

// Round 5
// 107.565 us; speedup vs baseline: 1.1161x; 1.0049x over previous
//
#include <hip/hip_runtime.h>

// SobelLoss: mean over 3 dirs of mean |sobel(moved) - sobel(label)|.
// conv(m)-conv(l) = conv(m-l); separable: s=[1,2,1], d=[-1,0,1]:
//   gx = sH(dW) rolled sD;  gy = dH(sW) rolled sD;  gz = sH(sW) rolled -dD.
//
// R15: volume-only attack; model refit after R14. Discovery: the tail
// prefetches staged 2 never-computed planes per chunk (clamped into the
// NEXT chunk => real HBM traffic). Actual staged planes: R13 12/8 (x1.5),
// R14 20/16 (x1.25); traffic 135/108.5 MB predicts 25/20us at a CONSTANT
// 5.4 TB/s (86% of achievable) -- kernel is AT the practical BW ceiling,
// volume is the only lever. This round: (1) clamp stage plane to the
// chunk's own halo (tail re-stages an L2-hot plane, ~free, keeps vmcnt
// uniform); (2) DC 16->32 => staged 34/32 = x1.0625, NBLK=240 (94% CU
// coverage, 240%8==0 keeps swizzle bijective); (3) rolled 11x3 loop +
// 1 peeled iter (full 34-iter unroll ~48KB > 32KB I$; triple keeps slot
// indices compile-time -- runtime slot => scratch, rule #20).
// Traffic ~92MB -> predicted sobel ~17us, total ~105us.
//
// Pipeline (R10, unchanged): asm global_load_dword pins issue order;
// 3 rotating plane slots, 2-ahead prefetch; s_waitcnt vmcnt(32) drains
// only the oldest plane (16 loads), keeping 32 in flight; "+v" ties stop
// compute hoisting above the wait.
// HARD-WON RULES: no min-waves __launch_bounds__ clamp (R2/R4 spill);
// NEVER __syncthreads in-loop; no in-graph memset (R11: partials->ws).

#define BB 2
#define DD 160
#define HH 192
#define WW 160
#define HW (HH * WW)

#define TH 6                    // output H rows per thread
#define DC 32                   // output D planes per block
#define NIT (DC + 2)            // 34
#define NR (TH + 2)             // 8 rows live per plane per wave
#define BH (4 * TH)             // 24 block output rows
#define HGRPS (HH / BH)         // 8
#define TILES (3 * HGRPS)       // 24 (wch + 3*hgrp)
#define DCH (DD / DC)           // 5
#define NTHREADS 256            // 4 waves/block

#define NBLK (TILES * DCH * BB)      // 240 partials
#define PER_XCD (NBLK / 8)           // 30 consecutive work-ids per XCD

#define GLOAD(dst, vo, sb) \
    asm volatile("global_load_dword %0, %1, %2" \
                 : "=v"(dst) : "v"(vo), "s"(sb) : "memory")

__global__ __launch_bounds__(NTHREADS)
__attribute__((amdgpu_waves_per_eu(1, 4)))
void sobel_loss_kernel(const float* __restrict__ moved,
                       const float* __restrict__ label,
                       float* __restrict__ out,
                       float* __restrict__ part)   // nullptr => atomic path
{
    __shared__ float red[4];

    // ---- XCD-contiguous work-id swizzle (bijective: 240 % 8 == 0) ----
    const int flat = blockIdx.x;
    const int swz  = (flat & 7) * PER_XCD + (flat >> 3);
    const int bx   = swz % TILES;        // tile: wch + 3*hgrp
    const int by   = (swz / TILES) % DCH;
    const int bz   = swz / (TILES * DCH);

    const int tid   = threadIdx.x;
    const int lane  = tid & 63;
    const int wavei = tid >> 6;                 // 0..3
    const int wch   = bx % 3;                   // W chunk: 62 outputs each
    const int hgrp  = bx / 3;                   // 0..7
    const int hbase = hgrp * BH + wavei * TH;   // 0..186
    const int d0    = by * DC;                  // 5 chunks
    const int base_b = bz * (DD * HW);
    // stage planes only within this chunk's halo [d0-1, d0+DC]
    const int pmax  = min(d0 + DC, DD - 1);

    // lane l holds column w = w0 + l - 1; outputs live on lanes 1..62
    const int  w0 = wch * 62;                   // 0, 62, 124
    const int  w  = w0 + lane - 1;              // -1 .. 186
    const bool wv = (unsigned)w < (unsigned)WW;
    const int  gw = min(max(w, 0), WW - 1);
    const bool outv = (lane >= 1) && (lane <= 62) && (w < WW);

    // per-row byte voffsets (fixed across D); OOB rows clamped, masked later
    int  voff[NR];
    bool rv[NR];
#pragma unroll
    for (int r = 0; r < NR; ++r) {
        const int gh = hbase - 1 + r;
        rv[r] = (unsigned)gh < (unsigned)HH;
        voff[r] = (min(max(gh, 0), HH - 1) * WW + gw) * 4;
    }

    // 3 rotating plane buffers; slot s=it%3 computed, s2=(it+2)%3 staged
    float bm[3][NR], bl[3][NR];

    {   // preload slot0 = plane d0-1 (clamped), slot1 = plane d0
        const float* pm = moved + base_b + max(d0 - 1, 0) * HW;
        const float* pl = label + base_b + max(d0 - 1, 0) * HW;
#pragma unroll
        for (int r = 0; r < NR; ++r) {
            GLOAD(bm[0][r], voff[r], pm);
            GLOAD(bl[0][r], voff[r], pl);
        }
        const float* qm = moved + base_b + d0 * HW;
        const float* ql = label + base_b + d0 * HW;
#pragma unroll
        for (int r = 0; r < NR; ++r) {
            GLOAD(bm[1][r], voff[r], qm);
            GLOAD(bl[1][r], voff[r], ql);
        }
    }   // outstanding: 32

    float px1[TH], px2[TH], py1[TH], py2[TH], pz1[TH], pz2[TH];
#pragma unroll
    for (int i = 0; i < TH; ++i) {
        px1[i] = px2[i] = 0.f;
        py1[i] = py2[i] = 0.f;
        pz1[i] = pz2[i] = 0.f;
    }
    float acc = 0.f;

    // One pipeline step: stage slot S2 (plane it+1, clamped to chunk),
    // drain to 32 outstanding (frees slot S = plane d0-1+it), compute.
#define ITER(ITV, S, S2) do {                                                \
        {                                                                    \
            const int p_ = min(d0 + (ITV) + 1, pmax);                        \
            const float* pm_ = moved + base_b + p_ * HW;                     \
            const float* pl_ = label + base_b + p_ * HW;                     \
            _Pragma("unroll")                                                \
            for (int r = 0; r < NR; ++r) {                                   \
                GLOAD(bm[S2][r], voff[r], pm_);                              \
                GLOAD(bl[S2][r], voff[r], pl_);                              \
            }                                                                \
        }   /* outstanding: 48 */                                            \
        asm volatile("s_waitcnt vmcnt(32)"                                   \
            : "+v"(bm[S][0]), "+v"(bm[S][1]), "+v"(bm[S][2]),                \
              "+v"(bm[S][3]), "+v"(bm[S][4]), "+v"(bm[S][5]),                \
              "+v"(bm[S][6]), "+v"(bm[S][7]),                                \
              "+v"(bl[S][0]), "+v"(bl[S][1]), "+v"(bl[S][2]),                \
              "+v"(bl[S][3]), "+v"(bl[S][4]), "+v"(bl[S][5]),                \
              "+v"(bl[S][6]), "+v"(bl[S][7]));                               \
        const bool pv_ = (unsigned)(d0 - 1 + (ITV)) < (unsigned)DD;          \
        float sW[NR], dW[NR];                                                \
        _Pragma("unroll")                                                    \
        for (int r = 0; r < NR; ++r) {                                       \
            const float d_ = (pv_ && rv[r] && wv) ? (bm[S][r] - bl[S][r])    \
                                                  : 0.f;                     \
            const float dl_ = __shfl_up(d_, 1, 64);    /* w-1, lane0 junk */ \
            const float dr_ = __shfl_down(d_, 1, 64);  /* w+1, ln63 junk */  \
            sW[r] = (dl_ + dr_) + 2.f * d_;   /* W-smooth */                 \
            dW[r] = dr_ - dl_;                /* W-deriv  */                 \
        }                                                                    \
        _Pragma("unroll")                                                    \
        for (int i = 0; i < TH; ++i) {                                       \
            const float px = (dW[i] + dW[i + 2]) + 2.f * dW[i + 1];          \
            const float pz = (sW[i] + sW[i + 2]) + 2.f * sW[i + 1];          \
            const float py = sW[i + 2] - sW[i];                              \
            if ((ITV) >= 2 && outv) {                                        \
                acc += fabsf(px2[i] + 2.f * px1[i] + px)    /* gx: sD */     \
                     + fabsf(py2[i] + 2.f * py1[i] + py)    /* gy: sD */     \
                     + fabsf(pz2[i] - pz);                  /* gz: dD */     \
            }                                                                \
            px2[i] = px1[i]; px1[i] = px;                                    \
            py2[i] = py1[i]; py1[i] = py;                                    \
            pz2[i] = pz1[i]; pz1[i] = pz;                                    \
        }                                                                    \
    } while (0)

    // 34 iterations = 11 rolled triples (compile-time slots) + 1 peeled.
#pragma unroll 1
    for (int itb = 0; itb < NIT - 1; itb += 3) {
        ITER(itb + 0, 0, 2);
        ITER(itb + 1, 1, 0);
        ITER(itb + 2, 2, 1);
    }
    ITER(NIT - 1, 0, 2);        // it=33: 33%3==0, (33+2)%3==2
#undef ITER

    // drain the 32 tail loads before reusing the memory pipe / ending
    asm volatile("s_waitcnt vmcnt(0)" ::: "memory");

    // ---- reduce: wave shuffle -> tiny LDS -> one store per block ----
#pragma unroll
    for (int off = 32; off > 0; off >>= 1)
        acc += __shfl_down(acc, off, 64);
    if (lane == 0) red[wavei] = acc;
    __syncthreads();
    if (tid == 0) {
        const float s = red[0] + red[1] + red[2] + red[3];
        if (part) {
            part[swz] = s;   // swz is a bijection of [0,NBLK)
        } else {
            atomicAdd(out, s * (1.0f / (3.0f * BB * DD * HH * WW)));
        }
    }
}

// Single-block final reduce: sum NBLK partials, scale, write out directly.
__global__ __launch_bounds__(256)
void sobel_reduce_kernel(const float* __restrict__ part,
                         float* __restrict__ out)
{
    __shared__ float red[4];
    float a = 0.f;
    for (int i = threadIdx.x; i < NBLK; i += 256)
        a += part[i];
#pragma unroll
    for (int off = 32; off > 0; off >>= 1)
        a += __shfl_down(a, off, 64);
    const int lane = threadIdx.x & 63;
    if (lane == 0) red[threadIdx.x >> 6] = a;
    __syncthreads();
    if (threadIdx.x == 0)
        out[0] = (red[0] + red[1] + red[2] + red[3])
                 * (1.0f / (3.0f * BB * DD * HH * WW));
}

extern "C" void kernel_launch(void* const* d_in, const int* in_sizes, int n_in,
                              void* d_out, int out_size, void* d_ws, size_t ws_size,
                              hipStream_t stream) {
    const float* moved = (const float*)d_in[0];
    const float* label = (const float*)d_in[1];
    float* out = (float*)d_out;
    (void)in_sizes; (void)n_in; (void)out_size;

    // flat 1D grid so the in-kernel XCD swizzle controls work placement
    dim3 grid(NBLK, 1, 1);          // 240 four-wave blocks, all resident

    if (d_ws != nullptr && ws_size >= NBLK * sizeof(float)) {
        float* part = (float*)d_ws;
        sobel_loss_kernel<<<grid, NTHREADS, 0, stream>>>(moved, label, out, part);
        sobel_reduce_kernel<<<1, 256, 0, stream>>>(part, out);
    } else {
        hipMemsetAsync(out, 0, sizeof(float), stream);
        sobel_loss_kernel<<<grid, NTHREADS, 0, stream>>>(moved, label, out, nullptr);
    }
}